// Round 12
// baseline (55.097 us; speedup 1.0000x reference)
//
#include <hip/hip_runtime.h>
#include <math.h>

#define BB   512
#define CC   3
#define HH   64
#define WW   32
#define HOUT 38
#define WOUT 16
#define HID  128
#define DD   114               // CC*HOUT
#define SEQP 120               // seq row pad: 60-float halves, 16B-aligned
#define WIHP 120               // Wih LDS row pad (words)
#define WHHP 132               // Whh LDS row pad (words); 132%32=4 -> banks spread
#define NPOOL (CC*HOUT*WOUT)   // 1824
#define XPAIR (2*CC*HH*WW)     // 12288 floats staged for the batch pair

typedef float f32x4 __attribute__((ext_vector_type(4)));

// fast tanh on the serial chain: exact saturation at +/-inf, ~1e-6 abs error
__device__ __forceinline__ float fast_tanh(float u) {
    return 1.f - 2.f / (__expf(2.f * u) + 1.f);
}

// ws layout (floats)
#define WS_SMEAN 0
#define WS_TMEAN 512

// ---- fused per-batch-PAIR kernel -------------------------------------------
// 256 blocks; block q handles batches 2q and 2q+1 with SHARED weight staging
// and register-resident weights. 4 waves; wave w owns rows [32w,32w+32);
// lane: kl = 32w+(l&31), kc = l>>5 is the K-half; split-K combines via
// __shfl_xor(32). Recurrence: 2 batches per step per barrier (2x ILP).
__global__ __launch_bounds__(256, 1)
void k1_fused(const float* __restrict__ x,
              const float* __restrict__ Wih,
              const float* __restrict__ Whh,
              const float* __restrict__ bih,
              const float* __restrict__ bhh,
              float* __restrict__ s_mean,
              float* __restrict__ t_mean)
{
    __shared__ __align__(16) float wst[HID * WHHP];   // 67.6 KB; x-pair/Wih/Whh
    __shared__ __align__(16) float seq0[WOUT][SEQP];  // 7.7 KB
    __shared__ __align__(16) float seq1[WOUT][SEQP];  // 7.7 KB
    __shared__ __align__(16) float hb0[2][HID];       // 1 KB
    __shared__ __align__(16) float hb1[2][HID];       // 1 KB
    __shared__ float red[2][4];
    __shared__ int   rowl[HOUT];

    const int tid  = threadIdx.x;
    const int wid  = tid >> 6;
    const int lane = tid & 63;
    const int kl   = (wid << 5) | (lane & 31);   // owned output row
    const int kc   = lane >> 5;                  // K-half (0/1)
    const int b0   = 2 * blockIdx.x;             // batch pair: b0, b0+1

    // --- issue x-pair loads FIRST (48 KB contiguous), then Wih prefetch ---
    f32x4 xpf[12];
    {
        const f32x4* xg = (const f32x4*)(x + (size_t)b0 * (CC*HH*WW));
        #pragma unroll
        for (int i = 0; i < 12; ++i) xpf[i] = xg[tid + 256*i];
    }
    f32x4 wihpf[14], wihtail;
    {
        const f32x4* wg = (const f32x4*)Wih;          // 3648 f4 total
        #pragma unroll
        for (int i = 0; i < 14; ++i) wihpf[i] = wg[tid + 256*i];
        if (tid < 64) wihtail = wg[3584 + tid];
    }

    // fractional-pool row starts (exact IEEE-f64 numpy match)
    if (tid < HOUT) {
        double alpha = (double)(HH - 2) / (double)(HOUT - 1);
        rowl[tid] = (tid < HOUT - 1)
            ? (int)(floor((tid + 0.5) * alpha) - floor(0.5 * alpha))
            : (HH - 2);
    }
    if (tid < HID) { hb0[0][tid] = 0.f; hb1[0][tid] = 0.f; }
    if (tid < 96) {
        seq0[tid / 6][DD + tid % 6] = 0.f;            // zero pad cols [114,120)
        seq1[tid / 6][DD + tid % 6] = 0.f;
    }

    // --- write x-pair to LDS (waits only on x; Wih stays in flight) ---
    {
        f32x4* xd = (f32x4*)wst;
        #pragma unroll
        for (int i = 0; i < 12; ++i) xd[tid + 256*i] = xpf[i];
    }
    __syncthreads();                                  // B1

    // --- pool + exact GELU for BOTH batches; two spatial sums ---
    float ps0 = 0.f, ps1 = 0.f;
    #pragma unroll
    for (int it = 0; it < 15; ++it) {
        int idx = tid + it*256;
        if (idx < 2*NPOOL) {
            int bsel = (idx >= NPOOL);
            int r0   = idx - bsel*NPOOL;
            int c  = r0 / (HOUT*WOUT);
            int r  = r0 % (HOUT*WOUT);
            int ho = r / WOUT;
            int wo = r % WOUT;
            const float* p0 = &wst[bsel*(CC*HH*WW) + c*(HH*WW) + rowl[ho]*WW + 2*wo];
            float m = fmaxf(fmaxf(p0[0], p0[1]), fmaxf(p0[WW], p0[WW+1]));
            float a = 0.5f * m * (1.f + erff(m * 0.70710678118654752440f));
            if (bsel) { ps1 += m; seq1[wo][c*HOUT + ho] = a; }
            else      { ps0 += m; seq0[wo][c*HOUT + ho] = a; }
        }
    }
    #pragma unroll
    for (int off = 32; off > 0; off >>= 1) {
        ps0 += __shfl_down(ps0, off);
        ps1 += __shfl_down(ps1, off);
    }
    if (lane == 0) { red[0][wid] = ps0; red[1][wid] = ps1; }
    __syncthreads();                                  // B2 (x reads done)
    if (tid < 2)
        s_mean[b0 + tid] = (red[tid][0] + red[tid][1] + red[tid][2] + red[tid][3])
                           * (1.f / (float)NPOOL);

    // --- Wih: LDS writes from prefetched regs into padded rows [128][120] ---
    #pragma unroll
    for (int i = 0; i < 14; ++i) {
        int j = 4*(tid + 256*i);
        #pragma unroll
        for (int e = 0; e < 4; ++e) {
            int r  = (j + e) / DD;                    // const-div -> magic mul
            int cc = (j + e) - r*DD;
            wst[r*WIHP + cc] = wihpf[i][e];
        }
    }
    if (tid < 64) {
        int j = 4*(3584 + tid);
        #pragma unroll
        for (int e = 0; e < 4; ++e) {
            int r  = (j + e) / DD;
            int cc = (j + e) - r*DD;
            wst[r*WIHP + cc] = wihtail[e];
        }
    }
    for (int j = tid; j < HID*6; j += 256)            // zero cols [114,120)
        wst[(j/6)*WIHP + DD + (j % 6)] = 0.f;
    __syncthreads();                                  // B3

    // wih regs: K-half kc of Wih row kl (60 floats)
    f32x4 wih[15];
    {
        const f32x4* wr = (const f32x4*)&wst[kl*WIHP + kc*60];
        #pragma unroll
        for (int dd = 0; dd < 15; ++dd) wih[dd] = wr[dd];
    }

    // --- issue full Whh prefetch (16 f4); latency hides under projection ---
    f32x4 whhpf[16];
    {
        const f32x4* hg = (const f32x4*)Whh;          // 4096 f4
        #pragma unroll
        for (int i = 0; i < 16; ++i) whhpf[i] = hg[tid + 256*i];
    }

    // --- projection for BOTH batches: zr0/zr1 complete in both kc lanes ---
    float zr0[WOUT], zr1[WOUT];
    #pragma unroll
    for (int t = 0; t < WOUT; ++t) {
        const f32x4* a4 = (const f32x4*)&seq0[t][kc*60];
        const f32x4* c4 = (const f32x4*)&seq1[t][kc*60];
        float s0 = 0.f, s1 = 0.f, s2 = 0.f, s3 = 0.f;
        float u0 = 0.f, u1 = 0.f, u2 = 0.f, u3 = 0.f;
        #pragma unroll
        for (int dd = 0; dd < 15; ++dd) {
            f32x4 a = a4[dd], c = c4[dd], w = wih[dd];
            s0 = fmaf(w.x, a.x, s0); u0 = fmaf(w.x, c.x, u0);
            s1 = fmaf(w.y, a.y, s1); u1 = fmaf(w.y, c.y, u1);
            s2 = fmaf(w.z, a.z, s2); u2 = fmaf(w.z, c.z, u2);
            s3 = fmaf(w.w, a.w, s3); u3 = fmaf(w.w, c.w, u3);
        }
        float p = (s0 + s1) + (s2 + s3);
        float q = (u0 + u1) + (u2 + u3);
        zr0[t] = p + __shfl_xor(p, 32);
        zr1[t] = q + __shfl_xor(q, 32);
    }
    {
        const float bias = bih[kl] + bhh[kl];
        #pragma unroll
        for (int t = 0; t < WOUT; ++t) { zr0[t] += bias; zr1[t] += bias; }
    }
    __syncthreads();                                  // B4 (wih copies done; wst free)

    // --- Whh: ONE staging round into padded rows [128][132] ---
    #pragma unroll
    for (int i = 0; i < 16; ++i) {
        int j4 = tid + 256*i;
        *(f32x4*)&wst[(j4 >> 5)*WHHP + ((j4 & 31) << 2)] = whhpf[i];
    }
    __syncthreads();                                  // B5
    f32x4 whh[16];
    {
        const f32x4* wr = (const f32x4*)&wst[kl*WHHP + (kc << 6)];
        #pragma unroll
        for (int dd = 0; dd < 16; ++dd) whh[dd] = wr[dd];
    }

    // --- 16-step recurrence, 2 batches per barrier (2x ILP) ---
    float hsum0 = 0.f, hsum1 = 0.f;
    #pragma unroll
    for (int t = 0; t < WOUT; ++t) {
        const int cur = t & 1, nxt = cur ^ 1;
        const f32x4* h40 = (const f32x4*)&hb0[cur][kc << 6];
        const f32x4* h41 = (const f32x4*)&hb1[cur][kc << 6];
        float s0 = 0.f, s1 = 0.f, s2 = 0.f, s3 = 0.f;
        float u0 = 0.f, u1 = 0.f, u2 = 0.f, u3 = 0.f;
        #pragma unroll
        for (int dd = 0; dd < 16; ++dd) {
            f32x4 hv = h40[dd], gv = h41[dd], w = whh[dd];
            s0 = fmaf(w.x, hv.x, s0); u0 = fmaf(w.x, gv.x, u0);
            s1 = fmaf(w.y, hv.y, s1); u1 = fmaf(w.y, gv.y, u1);
            s2 = fmaf(w.z, hv.z, s2); u2 = fmaf(w.z, gv.z, u2);
            s3 = fmaf(w.w, hv.w, s3); u3 = fmaf(w.w, gv.w, u3);
        }
        float p  = (s0 + s1) + (s2 + s3);
        float q  = (u0 + u1) + (u2 + u3);
        float v0 = zr0[t] + p + __shfl_xor(p, 32);
        float v1 = zr1[t] + q + __shfl_xor(q, 32);
        float hn0 = fast_tanh(v0);
        float hn1 = fast_tanh(v1);
        hsum0 += hn0; hsum1 += hn1;
        if (kc == 0) { hb0[nxt][kl] = hn0; hb1[nxt][kl] = hn1; }
        __syncthreads();                              // one barrier, two batches
    }
    if (kc == 0) {
        t_mean[(b0    )*HID + kl] = fast_tanh(hsum0 * (1.f / 16.f));
        t_mean[(b0 + 1)*HID + kl] = fast_tanh(hsum1 * (1.f / 16.f));
    }
}

// ---- k2: block (i, sub) writes out[i, 0, sub*2048 .. +2048) f4 -------------
__global__ __launch_bounds__(256)
void k2_out(const float* __restrict__ s_mean,
            const float* __restrict__ t_mean,
            f32x4* __restrict__ out)
{
    const int i   = blockIdx.x >> 3;           // batch row (512)
    const int sub = blockIdx.x & 7;            // eighth of a row
    const float s = s_mean[i];
    const f32x4* t4 = (const f32x4*)t_mean + sub*2048;
    f32x4*       o  = out + (size_t)i*16384 + sub*2048;
    const int tid = threadIdx.x;
    #pragma unroll
    for (int j = 0; j < 8; ++j) {
        int idx = tid + j*256;
        o[idx] = s * t4[idx];
    }
}

extern "C" void kernel_launch(void* const* d_in, const int* in_sizes, int n_in,
                              void* d_out, int out_size, void* d_ws, size_t ws_size,
                              hipStream_t stream)
{
    const float* x   = (const float*)d_in[0];
    const float* Wih = (const float*)d_in[1];
    const float* Whh = (const float*)d_in[2];
    const float* bih = (const float*)d_in[3];
    const float* bhh = (const float*)d_in[4];

    float* ws     = (float*)d_ws;
    float* s_mean = ws + WS_SMEAN;
    float* t_mean = ws + WS_TMEAN;

    k1_fused<<<dim3(BB/2), dim3(256), 0, stream>>>(x, Wih, Whh, bih, bhh, s_mean, t_mean);
    k2_out  <<<dim3(4096), dim3(256), 0, stream>>>(s_mean, t_mean, (f32x4*)d_out);
}

// Round 13
// 48.478 us; speedup vs baseline: 1.1365x; 1.1365x over previous
//
#include <hip/hip_runtime.h>
#include <math.h>

#define BB   512
#define CC   3
#define HH   64
#define WW   32
#define HOUT 38
#define WOUT 16
#define HID  128
#define DD   114               // CC*HOUT
#define SEQQ 36                // seq/h quarter stride (words): 16B-aligned, 4kc bank offset
#define SEQP 144               // 4*SEQQ
#define WIHP 132               // Wih LDS row pad (words); 132%32=4 -> banks spread
#define WHHP 132               // Whh LDS row pad (words)
#define NPOOL (CC*HOUT*WOUT)   // 1824

typedef float f32x4 __attribute__((ext_vector_type(4)));

// fast tanh on the serial chain: exact saturation at +/-inf, ~1e-6 abs error
__device__ __forceinline__ float fast_tanh(float u) {
    return 1.f - 2.f / (__expf(2.f * u) + 1.f);
}

// ws layout (floats)
#define WS_SMEAN 0
#define WS_TMEAN 512

// ---- fused per-batch kernel ------------------------------------------------
// 512 blocks x 512 threads (8 waves). Wave w owns rows [16w,16w+16);
// lane l: kl = 16w + (l&15), kc = l>>4 in {0..3} is the K-quarter.
// Split-K partials combine via shfl_xor(16)+shfl_xor(32). Recurrence:
// ONE barrier per step. 16 waves/CU (2 blocks/CU at ~78 KB LDS).
__global__ __launch_bounds__(512, 4)
void k1_fused(const float* __restrict__ x,
              const float* __restrict__ Wih,
              const float* __restrict__ Whh,
              const float* __restrict__ bih,
              const float* __restrict__ bhh,
              float* __restrict__ s_mean,
              float* __restrict__ t_mean)
{
    __shared__ __align__(16) float wst[HID * WHHP];  // 67.6 KB; x / Wih / Whh
    __shared__ __align__(16) float seq[WOUT][SEQP];  // 9.2 KB (4x36-word quarters)
    __shared__ __align__(16) float hbuf[2][SEQP];    // 1.2 KB
    __shared__ float red[8];
    __shared__ int   rowl[HOUT];

    const int tid  = threadIdx.x;
    const int wid  = tid >> 6;                   // wave 0..7
    const int lane = tid & 63;
    const int kl   = (wid << 4) | (lane & 15);   // owned output row 0..127
    const int kc   = lane >> 4;                  // K-quarter 0..3
    const int b    = blockIdx.x;

    // --- issue x loads FIRST (oldest in vmcnt FIFO), then Wih prefetch ---
    f32x4 xpf[3];
    {
        const f32x4* xg = (const f32x4*)(x + (size_t)b * (CC*HH*WW));
        #pragma unroll
        for (int i = 0; i < 3; ++i) xpf[i] = xg[tid + 512*i];
    }
    f32x4 wihpf[7], wihtail;
    {
        const f32x4* wg = (const f32x4*)Wih;          // 3648 f4 total
        #pragma unroll
        for (int i = 0; i < 7; ++i) wihpf[i] = wg[tid + 512*i];
        if (tid < 64) wihtail = wg[3584 + tid];
    }

    // fractional-pool row starts (exact IEEE-f64 numpy match)
    if (tid < HOUT) {
        double alpha = (double)(HH - 2) / (double)(HOUT - 1);
        rowl[tid] = (tid < HOUT - 1)
            ? (int)(floor((tid + 0.5) * alpha) - floor(0.5 * alpha))
            : (HH - 2);
    }
    if (tid < HID) hbuf[0][SEQQ*(tid >> 5) + (tid & 31)] = 0.f;
    if (tid < 224) {                              // zero seq cols 114..127 (q3)
        int t = tid / 14, o = 18 + tid % 14;
        seq[t][3*SEQQ + o] = 0.f;
    }

    // --- write x to LDS (waits only on x loads; Wih stays in flight) ---
    {
        f32x4* xd = (f32x4*)wst;
        #pragma unroll
        for (int i = 0; i < 3; ++i) xd[tid + 512*i] = xpf[i];
    }
    __syncthreads();                                  // B1

    // --- pool (2x2 fractional max) + exact GELU -> seq; spatial sum ---
    float ps = 0.f;
    #pragma unroll
    for (int it = 0; it < 4; ++it) {
        int idx = tid + it*512;
        if (idx < NPOOL) {
            int c  = idx / (HOUT*WOUT);
            int r  = idx % (HOUT*WOUT);
            int ho = r / WOUT;
            int wo = r % WOUT;
            const float* p0 = &wst[c*(HH*WW) + rowl[ho]*WW + 2*wo];
            float m = fmaxf(fmaxf(p0[0], p0[1]), fmaxf(p0[WW], p0[WW+1]));
            ps += m;
            int d = c*HOUT + ho;
            seq[wo][SEQQ*(d >> 5) + (d & 31)] =
                0.5f * m * (1.f + erff(m * 0.70710678118654752440f));
        }
    }
    #pragma unroll
    for (int off = 32; off > 0; off >>= 1) ps += __shfl_down(ps, off);
    if (lane == 0) red[wid] = ps;
    __syncthreads();                                  // B2 (x reads done; wst reusable)
    if (tid == 0) {
        float r = 0.f;
        #pragma unroll
        for (int i = 0; i < 8; ++i) r += red[i];
        s_mean[b] = r * (1.f / (float)NPOOL);
    }

    // --- Wih: LDS writes from prefetched regs into padded rows [128][132] ---
    #pragma unroll
    for (int i = 0; i < 7; ++i) {
        int j = 4*(tid + 512*i);
        #pragma unroll
        for (int e = 0; e < 4; ++e) {
            int r  = (j + e) / DD;                    // const-div -> magic mul
            int cc = (j + e) - r*DD;
            wst[r*WIHP + cc] = wihpf[i][e];
        }
    }
    if (tid < 64) {
        int j = 4*(3584 + tid);
        #pragma unroll
        for (int e = 0; e < 4; ++e) {
            int r  = (j + e) / DD;
            int cc = (j + e) - r*DD;
            wst[r*WIHP + cc] = wihtail[e];
        }
    }
    for (int j = tid; j < HID*14; j += 512)           // zero cols [114,128)
        wst[(j/14)*WIHP + DD + (j % 14)] = 0.f;
    __syncthreads();                                  // B3

    // wih regs: K-quarter kc of Wih row kl (32 floats)
    f32x4 wih[8];
    {
        const f32x4* wr = (const f32x4*)&wst[kl*WIHP + (kc << 5)];
        #pragma unroll
        for (int dd = 0; dd < 8; ++dd) wih[dd] = wr[dd];
    }

    // --- issue full Whh prefetch (8 f4); latency hides under projection ---
    f32x4 whhpf[8];
    {
        const f32x4* hg = (const f32x4*)Whh;          // 4096 f4
        #pragma unroll
        for (int i = 0; i < 8; ++i) whhpf[i] = hg[tid + 512*i];
    }

    // --- projection: zreg[t] complete in ALL lanes via 2-level shfl ---
    float zreg[WOUT];
    #pragma unroll
    for (int t = 0; t < WOUT; ++t) {
        const f32x4* a4 = (const f32x4*)&seq[t][kc*SEQQ];  // 4 bcast streams
        float s0 = 0.f, s1 = 0.f, s2 = 0.f, s3 = 0.f;
        #pragma unroll
        for (int dd = 0; dd < 8; ++dd) {
            f32x4 a = a4[dd], w = wih[dd];
            s0 = fmaf(w.x, a.x, s0);
            s1 = fmaf(w.y, a.y, s1);
            s2 = fmaf(w.z, a.z, s2);
            s3 = fmaf(w.w, a.w, s3);
        }
        float p = (s0 + s1) + (s2 + s3);
        p += __shfl_xor(p, 16);
        zreg[t] = p + __shfl_xor(p, 32);
    }
    {
        const float bias = bih[kl] + bhh[kl];
        #pragma unroll
        for (int t = 0; t < WOUT; ++t) zreg[t] += bias;
    }
    __syncthreads();                                  // B4 (wih copies done; wst free)

    // --- Whh: ONE staging round into padded rows [128][132] ---
    #pragma unroll
    for (int i = 0; i < 8; ++i) {
        int j4 = tid + 512*i;
        *(f32x4*)&wst[(j4 >> 5)*WHHP + ((j4 & 31) << 2)] = whhpf[i];
    }
    __syncthreads();                                  // B5
    f32x4 whh[8];
    {
        const f32x4* wr = (const f32x4*)&wst[kl*WHHP + (kc << 5)];
        #pragma unroll
        for (int dd = 0; dd < 8; ++dd) whh[dd] = wr[dd];
    }

    // --- 16-step recurrence: 2-shfl combine, ONE barrier/step ---
    float hsum = 0.f;
    #pragma unroll
    for (int t = 0; t < WOUT; ++t) {
        const int cur = t & 1, nxt = cur ^ 1;
        const f32x4* h4 = (const f32x4*)&hbuf[cur][kc*SEQQ];  // 4 bcast streams
        float s0 = 0.f, s1 = 0.f, s2 = 0.f, s3 = 0.f;
        #pragma unroll
        for (int dd = 0; dd < 8; ++dd) {
            f32x4 hv = h4[dd], w = whh[dd];
            s0 = fmaf(w.x, hv.x, s0);
            s1 = fmaf(w.y, hv.y, s1);
            s2 = fmaf(w.z, hv.z, s2);
            s3 = fmaf(w.w, hv.w, s3);
        }
        float p = (s0 + s1) + (s2 + s3);
        p += __shfl_xor(p, 16);
        float u  = zreg[t] + p + __shfl_xor(p, 32);
        float hn = fast_tanh(u);
        hsum += hn;
        if (kc == 0) hbuf[nxt][SEQQ*(kl >> 5) + (kl & 31)] = hn;
        __syncthreads();                              // h publish (one per step)
    }
    if (kc == 0) t_mean[b*HID + kl] = fast_tanh(hsum * (1.f / 16.f));
}

// ---- k2: block (i, sub) writes out[i, 0, sub*2048 .. +2048) f4 -------------
__global__ __launch_bounds__(256)
void k2_out(const float* __restrict__ s_mean,
            const float* __restrict__ t_mean,
            f32x4* __restrict__ out)
{
    const int i   = blockIdx.x >> 3;           // batch row (512)
    const int sub = blockIdx.x & 7;            // eighth of a row
    const float s = s_mean[i];
    const f32x4* t4 = (const f32x4*)t_mean + sub*2048;
    f32x4*       o  = out + (size_t)i*16384 + sub*2048;
    const int tid = threadIdx.x;
    #pragma unroll
    for (int j = 0; j < 8; ++j) {
        int idx = tid + j*256;
        o[idx] = s * t4[idx];
    }
}

extern "C" void kernel_launch(void* const* d_in, const int* in_sizes, int n_in,
                              void* d_out, int out_size, void* d_ws, size_t ws_size,
                              hipStream_t stream)
{
    const float* x   = (const float*)d_in[0];
    const float* Wih = (const float*)d_in[1];
    const float* Whh = (const float*)d_in[2];
    const float* bih = (const float*)d_in[3];
    const float* bhh = (const float*)d_in[4];

    float* ws     = (float*)d_ws;
    float* s_mean = ws + WS_SMEAN;
    float* t_mean = ws + WS_TMEAN;

    k1_fused<<<dim3(BB), dim3(512), 0, stream>>>(x, Wih, Whh, bih, bhh, s_mean, t_mean);
    k2_out  <<<dim3(4096), dim3(256), 0, stream>>>(s_mean, t_mean, (f32x4*)d_out);
}